// Round 2
// baseline (608.379 us; speedup 1.0000x reference)
//
#include <hip/hip_runtime.h>

// PScan: Y_t = A_t Y_{t-1} + X_t over L=2048, for B*C=64 chains of 16x16 fp32.
// 3-pass chunked scan, wave-synchronous (no __syncthreads anywhere):
//   pass1: 4096 chunks (S=32 steps) -> (Aagg, Xagg) per chunk
//   pass2: 64 chains, sequential scan over 64 chunk aggregates -> exclusive carry
//   pass3: re-apply recurrence per chunk from carry, write Y
// Layout: one 16-lane group per chunk (lane owns a 4x4 block), 4 chunks per wave.
// All cross-lane exchange via LDS within a single wave (in-order LDS pipe, no barriers).

constexpr int B_ = 4, L_ = 2048, C_ = 16;
constexpr int G_ = 64;          // chunks per chain
constexpr int S_ = 32;          // steps per chunk
constexpr int RS = 272;         // LDS region stride per chunk (dwords): 16*16 + 16 -> d*RS mod 32 = {0,16}

// swizzled offset of (row, 16B-block kb) inside a 16x16 matrix region.
// Rotating kb by (row>>2) spreads the 4 row-groups across banks; keeps 16B alignment.
__device__ __forceinline__ int swz(int row, int kb) {
    return row * 16 + (((kb + (row >> 2)) & 3) << 2);
}

// ---------------- pass 1: chunk aggregates ----------------
__global__ __launch_bounds__(64) void pass1(const float* __restrict__ A,
                                            const float* __restrict__ X,
                                            float* __restrict__ ws) {
    const int lane = threadIdx.x & 63;
    const int d    = lane >> 4;          // chunk-in-wave
    const int p    = lane & 15;
    const int i0   = (p >> 2) << 2;      // row block
    const int j0   = (p & 3) << 2;       // col block
    const int i0g  = p >> 2;
    const int j0g  = p & 3;

    long base4[4];
#pragma unroll
    for (int dd = 0; dd < 4; ++dd) {
        const int ch = blockIdx.x * 4 + dd;
        const int bc = ch >> 6, g = ch & 63;
        base4[dd] = ((((long)(bc >> 4)) * L_ + (long)g * S_) * C_ + (bc & 15)) * 256;
    }
    const long lstep  = (long)C_ * 256;
    const long mybase = base4[d];

    __shared__ float sA[2][4 * RS];
    __shared__ float aT[4 * RS];
    __shared__ float xT[4 * RS];

    const int soff = swz(lane >> 2, lane & 3);   // staging slot for this lane

    // load + stage A_0
    float4 preA[4];
#pragma unroll
    for (int dd = 0; dd < 4; ++dd) preA[dd] = *(const float4*)(A + base4[dd] + 4 * lane);
#pragma unroll
    for (int dd = 0; dd < 4; ++dd) *(float4*)&sA[0][dd * RS + soff] = preA[dd];

    // load X_0 block
    float4 preX[4];
#pragma unroll
    for (int r = 0; r < 4; ++r)
        preX[r] = *(const float4*)(X + mybase + (i0 + r) * 16 + j0);

    // prefetch A_1
#pragma unroll
    for (int dd = 0; dd < 4; ++dd)
        preA[dd] = *(const float4*)(A + base4[dd] + lstep + 4 * lane);

    // init agg after step 0: aggA = A_0, aggX = X_0.   nA[cc][r] = agg[i0+r][j0+cc]
    float nA[4][4], nX[4][4];
#pragma unroll
    for (int r = 0; r < 4; ++r) {
        float av[4], xv[4];
        *(float4*)av = *(const float4*)&sA[0][d * RS + swz(i0 + r, j0g)];
        *(float4*)xv = preX[r];
#pragma unroll
        for (int cc = 0; cc < 4; ++cc) { nA[cc][r] = av[cc]; nX[cc][r] = xv[cc]; }
    }

    int cur = 0;
    for (int t = 1; t < S_; ++t) {
        cur ^= 1;
        // stage A_t (already in preA)
#pragma unroll
        for (int dd = 0; dd < 4; ++dd) *(float4*)&sA[cur][dd * RS + soff] = preA[dd];
        // publish agg_{t-1} transposed: aT[j][k] = agg[k][j]
#pragma unroll
        for (int cc = 0; cc < 4; ++cc) {
            *(float4*)&aT[d * RS + swz(j0 + cc, i0g)] =
                make_float4(nA[cc][0], nA[cc][1], nA[cc][2], nA[cc][3]);
            *(float4*)&xT[d * RS + swz(j0 + cc, i0g)] =
                make_float4(nX[cc][0], nX[cc][1], nX[cc][2], nX[cc][3]);
        }
        // grab X_t (prefetched last iter)
        float xt[4][4];
#pragma unroll
        for (int r = 0; r < 4; ++r) {
            float xv[4]; *(float4*)xv = preX[r];
#pragma unroll
            for (int cc = 0; cc < 4; ++cc) xt[cc][r] = xv[cc];
        }
        // prefetch t+1 (clamped; harmless re-read on last iter)
        const int tn = (t + 1 < S_) ? (t + 1) : (S_ - 1);
#pragma unroll
        for (int dd = 0; dd < 4; ++dd)
            preA[dd] = *(const float4*)(A + base4[dd] + (long)tn * lstep + 4 * lane);
#pragma unroll
        for (int r = 0; r < 4; ++r)
            preX[r] = *(const float4*)(X + mybase + (long)tn * lstep + (i0 + r) * 16 + j0);

        // compute: newAgg = A_t * agg ;  newXagg = A_t * xagg + X_t
        float rA[4][4], rX[4][4];
#pragma unroll
        for (int cc = 0; cc < 4; ++cc)
#pragma unroll
            for (int r = 0; r < 4; ++r) { rA[cc][r] = 0.f; rX[cc][r] = xt[cc][r]; }
#pragma unroll
        for (int kb = 0; kb < 4; ++kb) {
            float ar[4][4], ta[4][4], tx[4][4];
#pragma unroll
            for (int r = 0; r < 4; ++r)
                *(float4*)ar[r] = *(const float4*)&sA[cur][d * RS + swz(i0 + r, kb)];
#pragma unroll
            for (int cc = 0; cc < 4; ++cc) {
                *(float4*)ta[cc] = *(const float4*)&aT[d * RS + swz(j0 + cc, kb)];
                *(float4*)tx[cc] = *(const float4*)&xT[d * RS + swz(j0 + cc, kb)];
            }
#pragma unroll
            for (int cc = 0; cc < 4; ++cc)
#pragma unroll
                for (int r = 0; r < 4; ++r)
#pragma unroll
                    for (int q = 0; q < 4; ++q) {
                        rA[cc][r] += ar[r][q] * ta[cc][q];
                        rX[cc][r] += ar[r][q] * tx[cc][q];
                    }
        }
#pragma unroll
        for (int cc = 0; cc < 4; ++cc)
#pragma unroll
            for (int r = 0; r < 4; ++r) { nA[cc][r] = rA[cc][r]; nX[cc][r] = rX[cc][r]; }
    }

    // write aggregates (row-major) to ws: slot = chunk*512 = [Aagg 256 | Xagg 256]
    const int chunk = blockIdx.x * 4 + d;
    float* slot = ws + (long)chunk * 512;
#pragma unroll
    for (int r = 0; r < 4; ++r) {
        *(float4*)(slot + (i0 + r) * 16 + j0) =
            make_float4(nA[0][r], nA[1][r], nA[2][r], nA[3][r]);
        *(float4*)(slot + 256 + (i0 + r) * 16 + j0) =
            make_float4(nX[0][r], nX[1][r], nX[2][r], nX[3][r]);
    }
}

// ---------------- pass 2: scan chunk aggregates per chain ----------------
// One wave per chain; lane owns a 2x2 block. Writes EXCLUSIVE carry over Xagg slot.
__global__ __launch_bounds__(64) void pass2(float* __restrict__ ws) {
    const int lane = threadIdx.x & 63;
    const int r0 = (lane >> 3) << 1;   // 0..14
    const int c0 = (lane & 7) << 1;    // 0..14
    float* base = ws + (long)blockIdx.x * G_ * 512;

    __shared__ float cT[16 * 20];      // cT[j*20 + i] = carry[i][j], rows padded to 20

    float cy[2][2] = {{0.f, 0.f}, {0.f, 0.f}};

    float4 Ag[2][4]; float2 Xg[2];
#pragma unroll
    for (int rr = 0; rr < 2; ++rr) {
#pragma unroll
        for (int kb = 0; kb < 4; ++kb)
            Ag[rr][kb] = *(const float4*)(base + (r0 + rr) * 16 + kb * 4);
        Xg[rr] = *(const float2*)(base + 256 + (r0 + rr) * 16 + c0);
    }

    for (int g = 0; g < G_; ++g) {
        float* slot = base + (long)g * 512;
        // prefetch next aggregate (carry-independent)
        const int gn = (g + 1 < G_) ? (g + 1) : g;
        float* nslot = base + (long)gn * 512;
        float4 nAg[2][4]; float2 nXg[2];
#pragma unroll
        for (int rr = 0; rr < 2; ++rr) {
#pragma unroll
            for (int kb = 0; kb < 4; ++kb)
                nAg[rr][kb] = *(const float4*)(nslot + (r0 + rr) * 16 + kb * 4);
            nXg[rr] = *(const float2*)(nslot + 256 + (r0 + rr) * 16 + c0);
        }
        // write exclusive carry over this slot's Xagg
#pragma unroll
        for (int rr = 0; rr < 2; ++rr)
            *(float2*)(slot + 256 + (r0 + rr) * 16 + c0) = make_float2(cy[rr][0], cy[rr][1]);
        // exchange carry (transposed) via LDS
#pragma unroll
        for (int cc = 0; cc < 2; ++cc) {
            cT[(c0 + cc) * 20 + r0 + 0] = cy[0][cc];
            cT[(c0 + cc) * 20 + r0 + 1] = cy[1][cc];
        }
        // carry_new = Aagg * carry + Xagg
        float nc[2][2] = {{Xg[0].x, Xg[0].y}, {Xg[1].x, Xg[1].y}};
#pragma unroll
        for (int kb = 0; kb < 4; ++kb) {
            float t0[4], t1[4], a0[4], a1[4];
            *(float4*)t0 = *(const float4*)&cT[(c0 + 0) * 20 + kb * 4];
            *(float4*)t1 = *(const float4*)&cT[(c0 + 1) * 20 + kb * 4];
            *(float4*)a0 = Ag[0][kb];
            *(float4*)a1 = Ag[1][kb];
#pragma unroll
            for (int q = 0; q < 4; ++q) {
                nc[0][0] += a0[q] * t0[q];
                nc[0][1] += a0[q] * t1[q];
                nc[1][0] += a1[q] * t0[q];
                nc[1][1] += a1[q] * t1[q];
            }
        }
#pragma unroll
        for (int rr = 0; rr < 2; ++rr) {
            cy[rr][0] = nc[rr][0]; cy[rr][1] = nc[rr][1];
            Xg[rr] = nXg[rr];
#pragma unroll
            for (int kb = 0; kb < 4; ++kb) Ag[rr][kb] = nAg[rr][kb];
        }
    }
}

// ---------------- pass 3: apply carry, write Y ----------------
__global__ __launch_bounds__(64) void pass3(const float* __restrict__ A,
                                            const float* __restrict__ X,
                                            const float* __restrict__ ws,
                                            float* __restrict__ out) {
    const int lane = threadIdx.x & 63;
    const int d    = lane >> 4;
    const int p    = lane & 15;
    const int i0   = (p >> 2) << 2;
    const int j0   = (p & 3) << 2;
    const int i0g  = p >> 2;

    long base4[4];
#pragma unroll
    for (int dd = 0; dd < 4; ++dd) {
        const int ch = blockIdx.x * 4 + dd;
        const int bc = ch >> 6, g = ch & 63;
        base4[dd] = ((((long)(bc >> 4)) * L_ + (long)g * S_) * C_ + (bc & 15)) * 256;
    }
    const long lstep  = (long)C_ * 256;
    const long mybase = base4[d];

    __shared__ float sA[2][4 * RS];
    __shared__ float yT[4 * RS];

    const int soff = swz(lane >> 2, lane & 3);

    // init Y = exclusive carry
    const int chunk = blockIdx.x * 4 + d;
    const float* cslot = ws + (long)chunk * 512 + 256;
    float nY[4][4];
#pragma unroll
    for (int r = 0; r < 4; ++r) {
        float cv[4]; *(float4*)cv = *(const float4*)(cslot + (i0 + r) * 16 + j0);
#pragma unroll
        for (int cc = 0; cc < 4; ++cc) nY[cc][r] = cv[cc];
    }

    float4 preA[4], preX[4];
#pragma unroll
    for (int dd = 0; dd < 4; ++dd) preA[dd] = *(const float4*)(A + base4[dd] + 4 * lane);
#pragma unroll
    for (int r = 0; r < 4; ++r)
        preX[r] = *(const float4*)(X + mybase + (i0 + r) * 16 + j0);

    int cur = 1;
    for (int t = 0; t < S_; ++t) {
        cur ^= 1;
        // stage A_t
#pragma unroll
        for (int dd = 0; dd < 4; ++dd) *(float4*)&sA[cur][dd * RS + soff] = preA[dd];
        // publish Y_{t-1} transposed
#pragma unroll
        for (int cc = 0; cc < 4; ++cc)
            *(float4*)&yT[d * RS + swz(j0 + cc, i0g)] =
                make_float4(nY[cc][0], nY[cc][1], nY[cc][2], nY[cc][3]);
        // grab X_t
        float xt[4][4];
#pragma unroll
        for (int r = 0; r < 4; ++r) {
            float xv[4]; *(float4*)xv = preX[r];
#pragma unroll
            for (int cc = 0; cc < 4; ++cc) xt[cc][r] = xv[cc];
        }
        // prefetch t+1
        const int tn = (t + 1 < S_) ? (t + 1) : (S_ - 1);
#pragma unroll
        for (int dd = 0; dd < 4; ++dd)
            preA[dd] = *(const float4*)(A + base4[dd] + (long)tn * lstep + 4 * lane);
#pragma unroll
        for (int r = 0; r < 4; ++r)
            preX[r] = *(const float4*)(X + mybase + (long)tn * lstep + (i0 + r) * 16 + j0);

        // Y_t = A_t * Y_{t-1} + X_t
        float rY[4][4];
#pragma unroll
        for (int cc = 0; cc < 4; ++cc)
#pragma unroll
            for (int r = 0; r < 4; ++r) rY[cc][r] = xt[cc][r];
#pragma unroll
        for (int kb = 0; kb < 4; ++kb) {
            float ar[4][4], ty[4][4];
#pragma unroll
            for (int r = 0; r < 4; ++r)
                *(float4*)ar[r] = *(const float4*)&sA[cur][d * RS + swz(i0 + r, kb)];
#pragma unroll
            for (int cc = 0; cc < 4; ++cc)
                *(float4*)ty[cc] = *(const float4*)&yT[d * RS + swz(j0 + cc, kb)];
#pragma unroll
            for (int cc = 0; cc < 4; ++cc)
#pragma unroll
                for (int r = 0; r < 4; ++r)
#pragma unroll
                    for (int q = 0; q < 4; ++q)
                        rY[cc][r] += ar[r][q] * ty[cc][q];
        }
#pragma unroll
        for (int cc = 0; cc < 4; ++cc)
#pragma unroll
            for (int r = 0; r < 4; ++r) nY[cc][r] = rY[cc][r];

        // store Y_t
#pragma unroll
        for (int r = 0; r < 4; ++r)
            *(float4*)(out + mybase + (long)t * lstep + (i0 + r) * 16 + j0) =
                make_float4(nY[0][r], nY[1][r], nY[2][r], nY[3][r]);
    }
}

extern "C" void kernel_launch(void* const* d_in, const int* in_sizes, int n_in,
                              void* d_out, int out_size, void* d_ws, size_t ws_size,
                              hipStream_t stream) {
    const float* A = (const float*)d_in[0];
    const float* X = (const float*)d_in[1];
    float* out = (float*)d_out;
    float* ws  = (float*)d_ws;   // 4096 chunks * 2 KB = 8 MB

    pass1<<<1024, 64, 0, stream>>>(A, X, ws);
    pass2<<<64, 64, 0, stream>>>(ws);
    pass3<<<1024, 64, 0, stream>>>(A, X, ws, out);
}

// Round 3
// 502.659 us; speedup vs baseline: 1.2103x; 1.2103x over previous
//
#include <hip/hip_runtime.h>

// PScan: Y_t = A_t Y_{t-1} + X_t over L=2048, for B*C=64 chains of 16x16 fp32.
// 3-pass chunked scan, wave-synchronous (no __syncthreads):
//   pass1: 8192 chunks (S=16 steps) -> (Aagg, Xagg) per chunk
//   pass2: 64 chains, sequential scan over 128 chunk aggregates -> exclusive carry
//   pass3: re-apply recurrence per chunk from carry, write Y
// Layout: one 16-lane group per chunk (lane owns a 4x4 block), 4 chunks per wave.
// S=16 (not 32): 8192 chunks x 16 lanes = 2048 waves = 8 waves/CU = 2/SIMD,
// fixing Round-2's fatal 1-wave/SIMD latency exposure (occupancy 10.8%, VALU 10%).

constexpr int B_ = 4, L_ = 2048, C_ = 16;
constexpr int G_ = 128;         // chunks per chain
constexpr int S_ = 16;          // steps per chunk
constexpr int RS = 272;         // LDS region stride per chunk (dwords)

// swizzled offset of (row, 16B-block kb) inside a 16x16 matrix region.
__device__ __forceinline__ int swz(int row, int kb) {
    return row * 16 + (((kb + (row >> 2)) & 3) << 2);
}

// ---------------- pass 1: chunk aggregates ----------------
__global__ __launch_bounds__(64) void pass1(const float* __restrict__ A,
                                            const float* __restrict__ X,
                                            float* __restrict__ ws) {
    const int lane = threadIdx.x & 63;
    const int d    = lane >> 4;          // chunk-in-wave
    const int p    = lane & 15;
    const int i0   = (p >> 2) << 2;      // row block
    const int j0   = (p & 3) << 2;       // col block
    const int i0g  = p >> 2;
    const int j0g  = p & 3;

    long base4[4];
#pragma unroll
    for (int dd = 0; dd < 4; ++dd) {
        const int ch = blockIdx.x * 4 + dd;
        const int bc = ch >> 7;          // ch / G_
        const int g  = ch & 127;
        base4[dd] = ((((long)(bc >> 4)) * L_ + (long)g * S_) * C_ + (bc & 15)) * 256;
    }
    const long lstep  = (long)C_ * 256;
    const long mybase = base4[d];

    __shared__ float sA[2][4 * RS];
    __shared__ float aT[4 * RS];
    __shared__ float xT[4 * RS];

    const int soff = swz(lane >> 2, lane & 3);   // staging slot for this lane

    // load + stage A_0
    float4 preA[4];
#pragma unroll
    for (int dd = 0; dd < 4; ++dd) preA[dd] = *(const float4*)(A + base4[dd] + 4 * lane);
#pragma unroll
    for (int dd = 0; dd < 4; ++dd) *(float4*)&sA[0][dd * RS + soff] = preA[dd];

    // load X_0 block
    float4 preX[4];
#pragma unroll
    for (int r = 0; r < 4; ++r)
        preX[r] = *(const float4*)(X + mybase + (i0 + r) * 16 + j0);

    // prefetch A_1
#pragma unroll
    for (int dd = 0; dd < 4; ++dd)
        preA[dd] = *(const float4*)(A + base4[dd] + lstep + 4 * lane);

    // init agg after step 0: aggA = A_0, aggX = X_0.   nA[cc][r] = agg[i0+r][j0+cc]
    float nA[4][4], nX[4][4];
#pragma unroll
    for (int r = 0; r < 4; ++r) {
        float av[4], xv[4];
        *(float4*)av = *(const float4*)&sA[0][d * RS + swz(i0 + r, j0g)];
        *(float4*)xv = preX[r];
#pragma unroll
        for (int cc = 0; cc < 4; ++cc) { nA[cc][r] = av[cc]; nX[cc][r] = xv[cc]; }
    }

    int cur = 0;
    for (int t = 1; t < S_; ++t) {
        cur ^= 1;
        // stage A_t (already in preA)
#pragma unroll
        for (int dd = 0; dd < 4; ++dd) *(float4*)&sA[cur][dd * RS + soff] = preA[dd];
        // publish agg_{t-1} transposed: aT[j][k] = agg[k][j]
#pragma unroll
        for (int cc = 0; cc < 4; ++cc) {
            *(float4*)&aT[d * RS + swz(j0 + cc, i0g)] =
                make_float4(nA[cc][0], nA[cc][1], nA[cc][2], nA[cc][3]);
            *(float4*)&xT[d * RS + swz(j0 + cc, i0g)] =
                make_float4(nX[cc][0], nX[cc][1], nX[cc][2], nX[cc][3]);
        }
        // grab X_t (prefetched last iter)
        float xt[4][4];
#pragma unroll
        for (int r = 0; r < 4; ++r) {
            float xv[4]; *(float4*)xv = preX[r];
#pragma unroll
            for (int cc = 0; cc < 4; ++cc) xt[cc][r] = xv[cc];
        }
        // prefetch t+1 (clamped; harmless re-read on last iter)
        const int tn = (t + 1 < S_) ? (t + 1) : (S_ - 1);
#pragma unroll
        for (int dd = 0; dd < 4; ++dd)
            preA[dd] = *(const float4*)(A + base4[dd] + (long)tn * lstep + 4 * lane);
#pragma unroll
        for (int r = 0; r < 4; ++r)
            preX[r] = *(const float4*)(X + mybase + (long)tn * lstep + (i0 + r) * 16 + j0);

        // compute: newAgg = A_t * agg ;  newXagg = A_t * xagg + X_t
        float rA[4][4], rX[4][4];
#pragma unroll
        for (int cc = 0; cc < 4; ++cc)
#pragma unroll
            for (int r = 0; r < 4; ++r) { rA[cc][r] = 0.f; rX[cc][r] = xt[cc][r]; }
#pragma unroll
        for (int kb = 0; kb < 4; ++kb) {
            float ar[4][4], ta[4][4], tx[4][4];
#pragma unroll
            for (int r = 0; r < 4; ++r)
                *(float4*)ar[r] = *(const float4*)&sA[cur][d * RS + swz(i0 + r, kb)];
#pragma unroll
            for (int cc = 0; cc < 4; ++cc) {
                *(float4*)ta[cc] = *(const float4*)&aT[d * RS + swz(j0 + cc, kb)];
                *(float4*)tx[cc] = *(const float4*)&xT[d * RS + swz(j0 + cc, kb)];
            }
#pragma unroll
            for (int cc = 0; cc < 4; ++cc)
#pragma unroll
                for (int r = 0; r < 4; ++r)
#pragma unroll
                    for (int q = 0; q < 4; ++q) {
                        rA[cc][r] += ar[r][q] * ta[cc][q];
                        rX[cc][r] += ar[r][q] * tx[cc][q];
                    }
        }
#pragma unroll
        for (int cc = 0; cc < 4; ++cc)
#pragma unroll
            for (int r = 0; r < 4; ++r) { nA[cc][r] = rA[cc][r]; nX[cc][r] = rX[cc][r]; }
    }

    // write aggregates (row-major) to ws: slot = chunk*512 = [Aagg 256 | Xagg 256]
    const int chunk = blockIdx.x * 4 + d;
    float* slot = ws + (long)chunk * 512;
#pragma unroll
    for (int r = 0; r < 4; ++r) {
        *(float4*)(slot + (i0 + r) * 16 + j0) =
            make_float4(nA[0][r], nA[1][r], nA[2][r], nA[3][r]);
        *(float4*)(slot + 256 + (i0 + r) * 16 + j0) =
            make_float4(nX[0][r], nX[1][r], nX[2][r], nX[3][r]);
    }
}

// ---------------- pass 2: scan chunk aggregates per chain ----------------
// One wave per chain; lane owns a 2x2 block. Writes EXCLUSIVE carry over Xagg slot.
__global__ __launch_bounds__(64) void pass2(float* __restrict__ ws) {
    const int lane = threadIdx.x & 63;
    const int r0 = (lane >> 3) << 1;   // 0..14
    const int c0 = (lane & 7) << 1;    // 0..14
    float* base = ws + (long)blockIdx.x * G_ * 512;

    __shared__ float cT[16 * 20];      // cT[j*20 + i] = carry[i][j], rows padded to 20

    float cy[2][2] = {{0.f, 0.f}, {0.f, 0.f}};

    float4 Ag[2][4]; float2 Xg[2];
#pragma unroll
    for (int rr = 0; rr < 2; ++rr) {
#pragma unroll
        for (int kb = 0; kb < 4; ++kb)
            Ag[rr][kb] = *(const float4*)(base + (r0 + rr) * 16 + kb * 4);
        Xg[rr] = *(const float2*)(base + 256 + (r0 + rr) * 16 + c0);
    }

    for (int g = 0; g < G_; ++g) {
        float* slot = base + (long)g * 512;
        // prefetch next aggregate (carry-independent)
        const int gn = (g + 1 < G_) ? (g + 1) : g;
        float* nslot = base + (long)gn * 512;
        float4 nAg[2][4]; float2 nXg[2];
#pragma unroll
        for (int rr = 0; rr < 2; ++rr) {
#pragma unroll
            for (int kb = 0; kb < 4; ++kb)
                nAg[rr][kb] = *(const float4*)(nslot + (r0 + rr) * 16 + kb * 4);
            nXg[rr] = *(const float2*)(nslot + 256 + (r0 + rr) * 16 + c0);
        }
        // write exclusive carry over this slot's Xagg
#pragma unroll
        for (int rr = 0; rr < 2; ++rr)
            *(float2*)(slot + 256 + (r0 + rr) * 16 + c0) = make_float2(cy[rr][0], cy[rr][1]);
        // exchange carry (transposed) via LDS
#pragma unroll
        for (int cc = 0; cc < 2; ++cc) {
            cT[(c0 + cc) * 20 + r0 + 0] = cy[0][cc];
            cT[(c0 + cc) * 20 + r0 + 1] = cy[1][cc];
        }
        // carry_new = Aagg * carry + Xagg
        float nc[2][2] = {{Xg[0].x, Xg[0].y}, {Xg[1].x, Xg[1].y}};
#pragma unroll
        for (int kb = 0; kb < 4; ++kb) {
            float t0[4], t1[4], a0[4], a1[4];
            *(float4*)t0 = *(const float4*)&cT[(c0 + 0) * 20 + kb * 4];
            *(float4*)t1 = *(const float4*)&cT[(c0 + 1) * 20 + kb * 4];
            *(float4*)a0 = Ag[0][kb];
            *(float4*)a1 = Ag[1][kb];
#pragma unroll
            for (int q = 0; q < 4; ++q) {
                nc[0][0] += a0[q] * t0[q];
                nc[0][1] += a0[q] * t1[q];
                nc[1][0] += a1[q] * t0[q];
                nc[1][1] += a1[q] * t1[q];
            }
        }
#pragma unroll
        for (int rr = 0; rr < 2; ++rr) {
            cy[rr][0] = nc[rr][0]; cy[rr][1] = nc[rr][1];
            Xg[rr] = nXg[rr];
#pragma unroll
            for (int kb = 0; kb < 4; ++kb) Ag[rr][kb] = nAg[rr][kb];
        }
    }
}

// ---------------- pass 3: apply carry, write Y ----------------
__global__ __launch_bounds__(64) void pass3(const float* __restrict__ A,
                                            const float* __restrict__ X,
                                            const float* __restrict__ ws,
                                            float* __restrict__ out) {
    const int lane = threadIdx.x & 63;
    const int d    = lane >> 4;
    const int p    = lane & 15;
    const int i0   = (p >> 2) << 2;
    const int j0   = (p & 3) << 2;
    const int i0g  = p >> 2;

    long base4[4];
#pragma unroll
    for (int dd = 0; dd < 4; ++dd) {
        const int ch = blockIdx.x * 4 + dd;
        const int bc = ch >> 7;
        const int g  = ch & 127;
        base4[dd] = ((((long)(bc >> 4)) * L_ + (long)g * S_) * C_ + (bc & 15)) * 256;
    }
    const long lstep  = (long)C_ * 256;
    const long mybase = base4[d];

    __shared__ float sA[2][4 * RS];
    __shared__ float yT[4 * RS];

    const int soff = swz(lane >> 2, lane & 3);

    // init Y = exclusive carry
    const int chunk = blockIdx.x * 4 + d;
    const float* cslot = ws + (long)chunk * 512 + 256;
    float nY[4][4];
#pragma unroll
    for (int r = 0; r < 4; ++r) {
        float cv[4]; *(float4*)cv = *(const float4*)(cslot + (i0 + r) * 16 + j0);
#pragma unroll
        for (int cc = 0; cc < 4; ++cc) nY[cc][r] = cv[cc];
    }

    float4 preA[4], preX[4];
#pragma unroll
    for (int dd = 0; dd < 4; ++dd) preA[dd] = *(const float4*)(A + base4[dd] + 4 * lane);
#pragma unroll
    for (int r = 0; r < 4; ++r)
        preX[r] = *(const float4*)(X + mybase + (i0 + r) * 16 + j0);

    int cur = 1;
    for (int t = 0; t < S_; ++t) {
        cur ^= 1;
        // stage A_t
#pragma unroll
        for (int dd = 0; dd < 4; ++dd) *(float4*)&sA[cur][dd * RS + soff] = preA[dd];
        // publish Y_{t-1} transposed
#pragma unroll
        for (int cc = 0; cc < 4; ++cc)
            *(float4*)&yT[d * RS + swz(j0 + cc, i0g)] =
                make_float4(nY[cc][0], nY[cc][1], nY[cc][2], nY[cc][3]);
        // grab X_t
        float xt[4][4];
#pragma unroll
        for (int r = 0; r < 4; ++r) {
            float xv[4]; *(float4*)xv = preX[r];
#pragma unroll
            for (int cc = 0; cc < 4; ++cc) xt[cc][r] = xv[cc];
        }
        // prefetch t+1
        const int tn = (t + 1 < S_) ? (t + 1) : (S_ - 1);
#pragma unroll
        for (int dd = 0; dd < 4; ++dd)
            preA[dd] = *(const float4*)(A + base4[dd] + (long)tn * lstep + 4 * lane);
#pragma unroll
        for (int r = 0; r < 4; ++r)
            preX[r] = *(const float4*)(X + mybase + (long)tn * lstep + (i0 + r) * 16 + j0);

        // Y_t = A_t * Y_{t-1} + X_t
        float rY[4][4];
#pragma unroll
        for (int cc = 0; cc < 4; ++cc)
#pragma unroll
            for (int r = 0; r < 4; ++r) rY[cc][r] = xt[cc][r];
#pragma unroll
        for (int kb = 0; kb < 4; ++kb) {
            float ar[4][4], ty[4][4];
#pragma unroll
            for (int r = 0; r < 4; ++r)
                *(float4*)ar[r] = *(const float4*)&sA[cur][d * RS + swz(i0 + r, kb)];
#pragma unroll
            for (int cc = 0; cc < 4; ++cc)
                *(float4*)ty[cc] = *(const float4*)&yT[d * RS + swz(j0 + cc, kb)];
#pragma unroll
            for (int cc = 0; cc < 4; ++cc)
#pragma unroll
                for (int r = 0; r < 4; ++r)
#pragma unroll
                    for (int q = 0; q < 4; ++q)
                        rY[cc][r] += ar[r][q] * ty[cc][q];
        }
#pragma unroll
        for (int cc = 0; cc < 4; ++cc)
#pragma unroll
            for (int r = 0; r < 4; ++r) nY[cc][r] = rY[cc][r];

        // store Y_t
#pragma unroll
        for (int r = 0; r < 4; ++r)
            *(float4*)(out + mybase + (long)t * lstep + (i0 + r) * 16 + j0) =
                make_float4(nY[0][r], nY[1][r], nY[2][r], nY[3][r]);
    }
}

extern "C" void kernel_launch(void* const* d_in, const int* in_sizes, int n_in,
                              void* d_out, int out_size, void* d_ws, size_t ws_size,
                              hipStream_t stream) {
    const float* A = (const float*)d_in[0];
    const float* X = (const float*)d_in[1];
    float* out = (float*)d_out;
    float* ws  = (float*)d_ws;   // 8192 chunks * 2 KB = 16 MB

    pass1<<<2048, 64, 0, stream>>>(A, X, ws);
    pass2<<<64, 64, 0, stream>>>(ws);
    pass3<<<2048, 64, 0, stream>>>(A, X, ws, out);
}